// Round 9
// baseline (346.845 us; speedup 1.0000x reference)
//
#include <hip/hip_runtime.h>

#define B_ 8
#define T_ 1024
#define CG_ 256
#define CAP2 26

// ---------------- pack: x (8,1024,1024) f32 -> tok rows (B*Cg, T) u8 ----------------
__global__ __launch_bounds__(256) void pack_kernel(const float* __restrict__ x,
                                                   unsigned char* __restrict__ tok){
  __shared__ unsigned char tl[256][80];
  const int b  = blockIdx.x >> 4;
  const int t0 = (blockIdx.x & 15) << 6;
  const int g  = threadIdx.x;
  const float* xb = x + ((size_t)(b*T_ + t0) * 1024) + g*4;
  for (int tt = 0; tt < 64; tt++){
    const float4 v = *reinterpret_cast<const float4*>(xb + (size_t)tt*1024);
    unsigned int t = (v.x>0.f?1u:0u) | (v.y>0.f?2u:0u) | (v.z>0.f?4u:0u) | (v.w>0.f?8u:0u);
    tl[g][tt] = (unsigned char)t;
  }
  __syncthreads();
  const int gg  = threadIdx.x >> 2;
  const int off = (threadIdx.x & 3) * 16;
  for (int it = 0; it < 4; it++){
    const int g2 = gg + it*64;
    const uint4 w = *reinterpret_cast<const uint4*>(&tl[g2][off]);
    *reinterpret_cast<uint4*>(tok + (size_t)(b*CG_ + g2)*T_ + t0 + off) = w;
  }
}

// Trigram-sparse ROSA DP.
//  run==1 argmax: lastpos1[x[i]]            (register, lane v holds value v)
//  run==2 argmax: lastpos2[(x[i-1],x[i])]   (256 u16 packed in 2 VGPRs)
//  run>=3 cells = trigram matches: bigram bucket entry = (x[j-2] 5b | j 11b);
//    verify x[j-2]==x[i-2] -> gather val[j-1]: fresh(stamp i-1) rn=run+1, stale rn=3.
//  Only trigram lanes gather/write; ~78% of steps skip the LDS DP entirely.
struct alignas(16) RowLds {
  unsigned int   val[1028];     // cells 0..1023, 1024 dummy-read, 1026 trash-write
  unsigned char  t[1040];       // tokens + pad
  unsigned short bg[256*CAP2];  // bigram buckets: (ver<<11)|j, sentinel 0xFC01
  unsigned int   cnt2[256];
};                              // 19488 B/wave, x4 = 77952 B -> 2 blocks/CU

#define SENT_E 0xFC01u          // ver=31 (never matches), j=1025

__global__ __launch_bounds__(256, 2) void rosa_tri_kernel(const unsigned char* __restrict__ tok,
                                                          unsigned char* __restrict__ pred){
  __shared__ RowLds S[4];
  const int wave = threadIdx.x >> 6;
  const unsigned int lane = threadIdx.x & 63u;
  const int row = blockIdx.x * 4 + wave;
  RowLds& R = S[wave];

  // stage tokens + pad
  { const uint4 v = *reinterpret_cast<const uint4*>(tok + (size_t)row*T_ + lane*16);
    *reinterpret_cast<uint4*>(&R.t[lane*16]) = v;
    if (lane == 0u) *reinterpret_cast<uint4*>(&R.t[1024]) = make_uint4(0,0,0,0); }
  // init val stamps to 0xFFFF (incl dummy/trash slots 1024..1027)
  { const uint4 z = make_uint4(0xFFFF0000u,0xFFFF0000u,0xFFFF0000u,0xFFFF0000u);
    uint4* p = reinterpret_cast<uint4*>(R.val);
    #pragma unroll
    for (int m = 0; m < 4; m++) p[m*64 + lane] = z;
    if (lane == 0u) p[256] = z; }
  // zero counters, fill bg with sentinel
  *reinterpret_cast<uint4*>(&R.cnt2[lane*4]) = make_uint4(0,0,0,0);
  { const unsigned int s2 = SENT_E | (SENT_E << 16);
    const uint4 s4 = make_uint4(s2,s2,s2,s2);
    uint4* p = reinterpret_cast<uint4*>(R.bg);
    #pragma unroll
    for (int m = 0; m < 13; m++) p[m*64 + lane] = s4; }
  // build buckets: entry = (ver<<11)|j, ver = (j>=2)? x[j-2] : 31
  #pragma unroll
  for (int k = 0; k < 16; k++){
    const unsigned int j = (unsigned)k*64u + lane;
    if (j >= 1u){
      const unsigned int v2 = ((unsigned)R.t[j-1] << 4) | (unsigned)R.t[j];
      const unsigned int ver = (j >= 2u) ? (unsigned)R.t[j-2] : 31u;
      const unsigned int r = atomicAdd(&R.cnt2[v2], 1u);
      if (r < (unsigned)CAP2) R.bg[v2*CAP2 + r] = (unsigned short)((ver << 11) | j);
    }
  }

  // tokens -> registers
  unsigned int vtokk[16];
  #pragma unroll
  for (int k = 0; k < 16; k++) vtokk[k] = R.t[k*64 + lane];

  unsigned int lp1 = 0xFFFFFFFFu;               // lane v: last j with x[j]==v (-1 none)
  unsigned int lpA = 0xFFFFFFFFu, lpB = 0xFFFFFFFFu; // lastpos2: 256 u16 over 2 regs
  unsigned int ans = 0u;
  const bool lane26 = (lane < (unsigned)CAP2);

  // rolling scalars + 2-deep bucket prefetch
  int s_xi  = __builtin_amdgcn_readlane((int)vtokk[0], 0);
  int s_xp1 = __builtin_amdgcn_readlane((int)vtokk[0], 1);
  int s_xm1 = 0;
  unsigned int s_xm2v = 30u;                    // verify target; 30 = never-match (i<2)
  unsigned int enA, enB;
  { const unsigned int b0 = (((unsigned)s_xm1 << 4) | (unsigned)s_xi);
    const unsigned int b1 = (((unsigned)s_xi  << 4) | (unsigned)s_xp1);
    enA = (unsigned int)R.bg[b0*CAP2 + lane];
    enB = (unsigned int)R.bg[b1*CAP2 + lane]; }

#define RSTEP(I0, DI, NEXTTOK_EXPR) do {                                          \
    const int i_ = (I0)*64 + (DI);                                                \
    const unsigned int en  = lane26 ? enA : SENT_E;                               \
    const unsigned int jl  = en & 0x7FFu;                                         \
    const unsigned int ver = en >> 11;                                            \
    const int s_xp2 = (NEXTTOK_EXPR);                                             \
    const unsigned int s_bn = (((unsigned)s_xp1 << 4) | (unsigned)s_xp2);         \
    const unsigned int enN = (unsigned int)R.bg[s_bn*CAP2 + lane];                \
    const bool trig = (ver == s_xm2v);                                            \
    /* run-1 scalar key */                                                        \
    const int s_lp1 = __builtin_amdgcn_readlane((int)lp1, s_xi);                  \
    unsigned int s_key = (s_lp1 < 0) ? 0u : (1024u + (unsigned)s_lp1);            \
    lp1 = (lane == (unsigned)s_xi) ? (unsigned)i_ : lp1;                          \
    /* run-2 scalar key via packed lastpos2 */                                    \
    const unsigned int s_v2 = (((unsigned)s_xm1 << 4) | (unsigned)s_xi);          \
    const unsigned int s_l2 = s_v2 & 63u;                                         \
    const unsigned int s_hi = (s_v2 >> 6) & 1u;                                   \
    const unsigned int s_sel = (s_v2 >> 7) & 1u;                                  \
    const unsigned int rA = (unsigned)__builtin_amdgcn_readlane((int)lpA, (int)s_l2); \
    const unsigned int rB = (unsigned)__builtin_amdgcn_readlane((int)lpB, (int)s_l2); \
    const unsigned int rr = s_sel ? rB : rA;                                      \
    const unsigned int s_lp2 = s_hi ? (rr >> 16) : (rr & 0xFFFFu);                \
    const unsigned int s_k2 = (s_lp2 != 0xFFFFu && i_ >= 1) ? (2048u + s_lp2) : 0u; \
    s_key = s_k2 > s_key ? s_k2 : s_key;                                          \
    { /* lastpos2 update (skip i==0) */                                           \
      const unsigned int s_sh = s_hi << 4;                                        \
      const unsigned int s_keep = ~(0xFFFFu << s_sh);                             \
      const unsigned int s_ins = ((unsigned)i_) << s_sh;                          \
      const bool lm = (lane == s_l2) && (i_ >= 1);                                \
      const unsigned int updA = (lpA & s_keep) | s_ins;                           \
      const unsigned int updB = (lpB & s_keep) | s_ins;                           \
      lpA = (lm && !s_sel) ? updA : lpA;                                          \
      lpB = (lm &&  s_sel) ? updB : lpB;                                          \
    }                                                                             \
    /* rare trigram path: gather + write + scalar-loop max */                     \
    const unsigned long long bm = __ballot(trig ? 1 : 0);                         \
    if (bm){                                                                      \
      const unsigned int g = R.val[jl - 1u];                                      \
      const unsigned int d = g - (((unsigned)(i_ - 1)) << 16);                    \
      const unsigned int rn = (d <= 1024u) ? (d + 1u) : 3u;                       \
      const unsigned int widx = trig ? jl : 1026u;                                \
      R.val[widx] = (((unsigned)i_) << 16) | rn;                                  \
      const unsigned int k3 = (rn << 10) | jl;                                    \
      const bool valid = trig && (jl < (unsigned)i_);                             \
      unsigned long long mv = __ballot(valid ? 1 : 0);                            \
      while (mv){                                                                 \
        const int l = (int)__builtin_ctzll(mv);                                   \
        const unsigned int kk = (unsigned)__builtin_amdgcn_readlane((int)k3, l);  \
        s_key = kk > s_key ? kk : s_key;                                          \
        mv &= mv - 1ull;                                                          \
      }                                                                           \
    }                                                                             \
    ans = (lane == (unsigned)(DI)) ? s_key : ans;                                 \
    s_xm2v = (i_ >= 1) ? (unsigned)s_xm1 : 30u;                                   \
    s_xm1 = s_xi; s_xi = s_xp1; s_xp1 = s_xp2;                                    \
    enA = enB; enB = enN;                                                         \
  } while(0)

  #pragma unroll
  for (int i0 = 0; i0 < 16; i0++){
    #pragma unroll 1
    for (int di = 0; di < 62; di++){
      RSTEP(i0, di, __builtin_amdgcn_readlane((int)vtokk[i0], di + 2));
    }
    RSTEP(i0, 62, __builtin_amdgcn_readlane((int)vtokk[(i0+1) & 15], (i0 < 15) ? 0 : 62));
    RSTEP(i0, 63, __builtin_amdgcn_readlane((int)vtokk[(i0+1) & 15], (i0 < 15) ? 1 : 63));
    // epilogue: lane s finalizes step i0*64+s
    const unsigned int ab = ans;
    unsigned int pidx = (ab & 1023u) + 1u;
    pidx = pidx > 1023u ? 1023u : pidx;
    const unsigned int pt = R.t[pidx];
    pred[(size_t)row*T_ + i0*64 + lane] = (unsigned char)((ab >= 1024u) ? pt : 0u);
    ans = 0u;
  }
#undef RSTEP
}

// ---------------- expand: pred (B*Cg, T) u8 -> out (B,T,C) f32 ----------------
__global__ __launch_bounds__(256) void expand_kernel(const unsigned char* __restrict__ pred,
                                                     const float* __restrict__ emb0,
                                                     const float* __restrict__ emb1,
                                                     float* __restrict__ out){
  __shared__ unsigned char pl[64][80];
  const int bid = blockIdx.x;
  const int g0 = (bid & 3) << 6;
  const int t0 = ((bid >> 2) & 15) << 6;
  const int b  = bid >> 6;
  const int k  = threadIdx.x;
  {
    const int gg = k >> 2, off = (k & 3) * 16;
    const uint4 v = *reinterpret_cast<const uint4*>(pred + (size_t)(b*CG_ + g0 + gg)*T_ + t0 + off);
    *reinterpret_cast<uint4*>(&pl[gg][off]) = v;
  }
  __syncthreads();
  const int gg = k & 63;
  const int w  = k >> 6;
  const float4 e0 = *reinterpret_cast<const float4*>(emb0 + (g0+gg)*4);
  const float4 e1 = *reinterpret_cast<const float4*>(emb1 + (g0+gg)*4);
  for (int it = 0; it < 16; it++){
    const int tt = it*4 + w;
    const unsigned int pb = pl[gg][tt];
    float4 o;
    o.x = (pb & 1u) ? e1.x : e0.x;
    o.y = (pb & 2u) ? e1.y : e0.y;
    o.z = (pb & 4u) ? e1.z : e0.z;
    o.w = (pb & 8u) ? e1.w : e0.w;
    *reinterpret_cast<float4*>(out + (size_t)(b*T_ + t0 + tt)*1024 + (g0+gg)*4) = o;
  }
}

extern "C" void kernel_launch(void* const* d_in, const int* in_sizes, int n_in,
                              void* d_out, int out_size, void* d_ws, size_t ws_size,
                              hipStream_t stream){
  const float* x    = (const float*)d_in[0];
  const float* emb0 = (const float*)d_in[1];
  const float* emb1 = (const float*)d_in[2];
  float* out = (float*)d_out;
  unsigned char* tok  = (unsigned char*)d_ws;
  unsigned char* pred = tok + (size_t)B_*CG_*T_;
  pack_kernel<<<128, 256, 0, stream>>>(x, tok);
  rosa_tri_kernel<<<(B_*CG_)/4, 256, 0, stream>>>(tok, pred);
  expand_kernel<<<512, 256, 0, stream>>>(pred, emb0, emb1, out);
}

// Round 10
// 241.894 us; speedup vs baseline: 1.4339x; 1.4339x over previous
//
#include <hip/hip_runtime.h>

#define B_ 8
#define T_ 1024
#define CG_ 256
#define CAP2 26
#define SENT_E 0xFC01u          // ver=31 (never matches), j=1025

// ---------------- pack: x (8,1024,1024) f32 -> tok rows (B*Cg, T) u8 ----------------
__global__ __launch_bounds__(256) void pack_kernel(const float* __restrict__ x,
                                                   unsigned char* __restrict__ tok){
  __shared__ unsigned char tl[256][80];
  const int b  = blockIdx.x >> 4;
  const int t0 = (blockIdx.x & 15) << 6;
  const int g  = threadIdx.x;
  const float* xb = x + ((size_t)(b*T_ + t0) * 1024) + g*4;
  for (int tt = 0; tt < 64; tt++){
    const float4 v = *reinterpret_cast<const float4*>(xb + (size_t)tt*1024);
    unsigned int t = (v.x>0.f?1u:0u) | (v.y>0.f?2u:0u) | (v.z>0.f?4u:0u) | (v.w>0.f?8u:0u);
    tl[g][tt] = (unsigned char)t;
  }
  __syncthreads();
  const int gg  = threadIdx.x >> 2;
  const int off = (threadIdx.x & 3) * 16;
  for (int it = 0; it < 4; it++){
    const int g2 = gg + it*64;
    const uint4 w = *reinterpret_cast<const uint4*>(&tl[g2][off]);
    *reinterpret_cast<uint4*>(tok + (size_t)(b*CG_ + g2)*T_ + t0 + off) = w;
  }
}

// Trigram-sparse ROSA DP, branch driven by a PRECOMPUTED per-step bitmap
// (no per-step ballot). Semantics identical to R9 (passed):
//   run-1 argmax: lastpos1 register (lane v holds last j with x[j]==v)
//   run-2 argmax: bucket entries, key 2048+j (exact: non-trig bucket cells have run==2)
//   run>=3: trigram-verified cells, val[] DP; stale -> rn=3, fresh -> rn=run+1.
struct alignas(16) RowLds {
  unsigned int   val[1028];     // cells 0..1023, [1024] dummy-read, [1026] trash-write
                                // build alias: val[0..511] = trigram nibble counters
  unsigned char  t[1040];       // tokens + pad
  unsigned short bg[256*CAP2];  // bigram buckets: (ver<<11)|j, sentinel SENT_E
  unsigned int   cnt2[256];
};                              // 19488 B/wave, x4 = 77952 B -> 2 blocks/CU

__global__ __launch_bounds__(256, 2) void rosa_tri2_kernel(const unsigned char* __restrict__ tok,
                                                           unsigned char* __restrict__ pred){
  __shared__ RowLds S[4];
  const int wave = threadIdx.x >> 6;
  const unsigned int lane = threadIdx.x & 63u;
  const int row = blockIdx.x * 4 + wave;
  RowLds& R = S[wave];

  // stage tokens + pad
  { const uint4 v = *reinterpret_cast<const uint4*>(tok + (size_t)row*T_ + lane*16);
    *reinterpret_cast<uint4*>(&R.t[lane*16]) = v;
    if (lane == 0u) *reinterpret_cast<uint4*>(&R.t[1024]) = make_uint4(0,0,0,0); }
  // zero cnt2 and cnt3 (cnt3 aliased over val[0..511])
  *reinterpret_cast<uint4*>(&R.cnt2[lane*4]) = make_uint4(0,0,0,0);
  { uint4* p = reinterpret_cast<uint4*>(R.val);
    p[lane] = make_uint4(0,0,0,0); p[lane+64] = make_uint4(0,0,0,0); }
  // fill bg with sentinel
  { const unsigned int s2 = SENT_E | (SENT_E << 16);
    const uint4 s4 = make_uint4(s2,s2,s2,s2);
    uint4* p = reinterpret_cast<uint4*>(R.bg);
    #pragma unroll
    for (int m = 0; m < 13; m++) p[m*64 + lane] = s4; }
  // build buckets + trigram nibble counts (same-wave DS ordering)
  #pragma unroll
  for (int k = 0; k < 16; k++){
    const unsigned int j = (unsigned)k*64u + lane;
    if (j >= 1u){
      const unsigned int tj   = R.t[j];
      const unsigned int tjm1 = R.t[j-1];
      const unsigned int v2 = (tjm1 << 4) | tj;
      const unsigned int ver = (j >= 2u) ? (unsigned)R.t[j-2] : 31u;
      const unsigned int r = atomicAdd(&R.cnt2[v2], 1u);
      if (r < (unsigned)CAP2) R.bg[v2*CAP2 + r] = (unsigned short)((ver << 11) | j);
      if (j >= 2u){
        const unsigned int tr = (((unsigned)R.t[j-2]) << 8) | (tjm1 << 4) | tj;
        atomicAdd(&R.val[tr >> 3], 1u << ((tr & 7u) * 4u));
      }
    }
  }
  // trigram-presence bitmap -> 2 VGPRs (lane c holds chunk c's lo/hi words)
  unsigned int vblo = 0u, vbhi = 0u;
  #pragma unroll
  for (int c = 0; c < 16; c++){
    const unsigned int ii = (unsigned)c*64u + lane;
    bool ta = false;
    if (ii >= 2u){
      const unsigned int tr = (((unsigned)R.t[ii-2]) << 8) | (((unsigned)R.t[ii-1]) << 4) | (unsigned)R.t[ii];
      ta = (((R.val[tr >> 3] >> ((tr & 7u) * 4u)) & 15u) >= 2u);
    }
    const unsigned long long bm = __ballot(ta ? 1 : 0);
    vblo = (lane == (unsigned)c) ? (unsigned int)bm : vblo;
    vbhi = (lane == (unsigned)c) ? (unsigned int)(bm >> 32) : vbhi;
  }
  // init val stamps to 0xFFFF (overwrites cnt3 alias)
  { const uint4 z = make_uint4(0xFFFF0000u,0xFFFF0000u,0xFFFF0000u,0xFFFF0000u);
    uint4* p = reinterpret_cast<uint4*>(R.val);
    #pragma unroll
    for (int m = 0; m < 4; m++) p[m*64 + lane] = z;
    if (lane == 0u) p[256] = z; }

  // tokens -> registers
  unsigned int vtokk[16];
  #pragma unroll
  for (int k = 0; k < 16; k++) vtokk[k] = R.t[k*64 + lane];

  unsigned int lp1 = 0xFFFFFFFFu;               // lane v: last j with x[j]==v (-1 none)
  unsigned int ans = 0u;
  const bool lane26 = (lane < (unsigned)CAP2);

  int s_xi  = __builtin_amdgcn_readlane((int)vtokk[0], 0);
  int s_xp1 = __builtin_amdgcn_readlane((int)vtokk[0], 1);
  int s_xm1 = 0;
  unsigned int s_xm2v = 30u;                    // x[i-2] (valid for i>=2; bitmap gates use)
  unsigned int enA, enB;
  { const unsigned int b0 = (((unsigned)s_xm1 << 4) | (unsigned)s_xi);
    const unsigned int b1 = (((unsigned)s_xi  << 4) | (unsigned)s_xp1);
    enA = (unsigned int)R.bg[b0*CAP2 + lane];
    enB = (unsigned int)R.bg[b1*CAP2 + lane]; }

#define RSTEP(I0, DI, NEXTTOK_EXPR) do {                                          \
    const int i_ = (I0)*64 + (DI);                                                \
    const unsigned int en  = lane26 ? enA : SENT_E;                               \
    const unsigned int jl  = en & 0x7FFu;                                         \
    const int s_xp2 = (NEXTTOK_EXPR);                                             \
    const unsigned int s_bn = (((unsigned)s_xp1 << 4) | (unsigned)s_xp2);         \
    const unsigned int enN = (unsigned int)R.bg[s_bn*CAP2 + lane];                \
    /* run-1 scalar key */                                                        \
    const int s_lp1 = __builtin_amdgcn_readlane((int)lp1, s_xi);                  \
    unsigned int s_key = (s_lp1 < 0) ? 0u : (1024u + (unsigned)s_lp1);            \
    lp1 = (lane == (unsigned)s_xi) ? (unsigned)i_ : lp1;                          \
    /* per-lane key: run-2 default; upgraded on (rare, precomputed) trig steps */ \
    unsigned int key = 2048u + jl;                                                \
    const unsigned int sw = ((DI) < 32) ? s_blo : s_bhi;                          \
    if ((sw >> ((DI) & 31)) & 1u){                                                \
      const unsigned int ver = en >> 11;                                          \
      const bool trig = (ver == s_xm2v);                                          \
      const unsigned int g = R.val[jl - 1u];                                      \
      const unsigned int d = g - (((unsigned)(i_ - 1)) << 16);                    \
      const unsigned int rn = (d <= 1024u) ? (d + 1u) : 3u;                       \
      const unsigned int widx = trig ? jl : 1026u;                                \
      R.val[widx] = (((unsigned)i_) << 16) | rn;                                  \
      const unsigned int k3 = (rn << 10) | jl;                                    \
      key = trig ? k3 : key;                                                      \
    }                                                                             \
    key = (jl < (unsigned)i_) ? key : 0u;                                         \
    { int bb = (int)key, tt;                                                      \
      tt = __builtin_amdgcn_mov_dpp(bb, 0x111, 0xf, 0xf, true); bb = ((unsigned)tt > (unsigned)bb) ? tt : bb; \
      tt = __builtin_amdgcn_mov_dpp(bb, 0x112, 0xf, 0xf, true); bb = ((unsigned)tt > (unsigned)bb) ? tt : bb; \
      tt = __builtin_amdgcn_mov_dpp(bb, 0x114, 0xf, 0xf, true); bb = ((unsigned)tt > (unsigned)bb) ? tt : bb; \
      tt = __builtin_amdgcn_mov_dpp(bb, 0x118, 0xf, 0xf, true); bb = ((unsigned)tt > (unsigned)bb) ? tt : bb; \
      const unsigned int r15 = (unsigned)__builtin_amdgcn_readlane(bb, 15);       \
      const unsigned int r31 = (unsigned)__builtin_amdgcn_readlane(bb, 31);       \
      const unsigned int rmx = r15 > r31 ? r15 : r31;                             \
      s_key = rmx > s_key ? rmx : s_key;                                          \
    }                                                                             \
    ans = (lane == (unsigned)(DI)) ? s_key : ans;                                 \
    s_xm2v = (unsigned)s_xm1;                                                     \
    s_xm1 = s_xi; s_xi = s_xp1; s_xp1 = s_xp2;                                    \
    enA = enB; enB = enN;                                                         \
  } while(0)

  #pragma unroll
  for (int i0 = 0; i0 < 16; i0++){
    const unsigned int s_blo = (unsigned)__builtin_amdgcn_readlane((int)vblo, i0);
    const unsigned int s_bhi = (unsigned)__builtin_amdgcn_readlane((int)vbhi, i0);
    #pragma unroll 1
    for (int di = 0; di < 62; di++){
      RSTEP(i0, di, __builtin_amdgcn_readlane((int)vtokk[i0], di + 2));
    }
    RSTEP(i0, 62, __builtin_amdgcn_readlane((int)vtokk[(i0+1) & 15], (i0 < 15) ? 0 : 62));
    RSTEP(i0, 63, __builtin_amdgcn_readlane((int)vtokk[(i0+1) & 15], (i0 < 15) ? 1 : 63));
    // epilogue: lane s finalizes step i0*64+s
    const unsigned int ab = ans;
    unsigned int pidx = (ab & 1023u) + 1u;
    pidx = pidx > 1023u ? 1023u : pidx;
    const unsigned int pt = R.t[pidx];
    pred[(size_t)row*T_ + i0*64 + lane] = (unsigned char)((ab >= 1024u) ? pt : 0u);
    ans = 0u;
  }
#undef RSTEP
}

// ---------------- expand: pred (B*Cg, T) u8 -> out (B,T,C) f32 ----------------
__global__ __launch_bounds__(256) void expand_kernel(const unsigned char* __restrict__ pred,
                                                     const float* __restrict__ emb0,
                                                     const float* __restrict__ emb1,
                                                     float* __restrict__ out){
  __shared__ unsigned char pl[64][80];
  const int bid = blockIdx.x;
  const int g0 = (bid & 3) << 6;
  const int t0 = ((bid >> 2) & 15) << 6;
  const int b  = bid >> 6;
  const int k  = threadIdx.x;
  {
    const int gg = k >> 2, off = (k & 3) * 16;
    const uint4 v = *reinterpret_cast<const uint4*>(pred + (size_t)(b*CG_ + g0 + gg)*T_ + t0 + off);
    *reinterpret_cast<uint4*>(&pl[gg][off]) = v;
  }
  __syncthreads();
  const int gg = k & 63;
  const int w  = k >> 6;
  const float4 e0 = *reinterpret_cast<const float4*>(emb0 + (g0+gg)*4);
  const float4 e1 = *reinterpret_cast<const float4*>(emb1 + (g0+gg)*4);
  for (int it = 0; it < 16; it++){
    const int tt = it*4 + w;
    const unsigned int pb = pl[gg][tt];
    float4 o;
    o.x = (pb & 1u) ? e1.x : e0.x;
    o.y = (pb & 2u) ? e1.y : e0.y;
    o.z = (pb & 4u) ? e1.z : e0.z;
    o.w = (pb & 8u) ? e1.w : e0.w;
    *reinterpret_cast<float4*>(out + (size_t)(b*T_ + t0 + tt)*1024 + (g0+gg)*4) = o;
  }
}

extern "C" void kernel_launch(void* const* d_in, const int* in_sizes, int n_in,
                              void* d_out, int out_size, void* d_ws, size_t ws_size,
                              hipStream_t stream){
  const float* x    = (const float*)d_in[0];
  const float* emb0 = (const float*)d_in[1];
  const float* emb1 = (const float*)d_in[2];
  float* out = (float*)d_out;
  unsigned char* tok  = (unsigned char*)d_ws;
  unsigned char* pred = tok + (size_t)B_*CG_*T_;
  pack_kernel<<<128, 256, 0, stream>>>(x, tok);
  rosa_tri2_kernel<<<(B_*CG_)/4, 256, 0, stream>>>(tok, pred);
  expand_kernel<<<512, 256, 0, stream>>>(pred, emb0, emb1, out);
}